// Round 6
// baseline (134.474 us; speedup 1.0000x reference)
//
#include <hip/hip_runtime.h>
#include <stdint.h>
#include <stddef.h>

// out[b, p*768+e] = sum_d x[b,d]*W[p,d]*GE[d,e] + bias[p]
// == per-b GEMM: OUT_b(256x768) = (diag(x_b) W)(256x2048) @ GT^T + bias
//
// R11 vs R10: all prior structures obey time = SUM(MFMA, LDS-read, LDS-write)
// cycles; m201's 62% is a better reads:MFMA ratio, not overlap. So shrink the
// sum: (1) 2-BATCH SHARING - one wave computes 2 b from the SAME W/GT LDS
// reads (W,GT are b-invariant; only diag(x) differs) -> reads/MFMA 0.46->0.25;
// acc 2x192 VGPR -> 4 waves, 1 wave/SIMD, launch_bounds(256,1) (cap 512, no
// spill till ~450). (2) depth-2 prefetch: stage t+1 at top of tile t, ONE
// __syncthreads per tile at bottom - its implicit vmcnt(0) drain waits on
// loads issued a full tile earlier (cheap), unlike R5's same-tile drain.
// (3) NO sched_barriers inside the tile: let the compiler interleave kh1
// ds_reads under kh0 MFMAs (the proven source-level overlap mechanism).
// Block = 2b x 128p x 192e, BK=64, wave tile 64x96 per b. Grid 32 bp x 2 ph
// x 4 ct = 256 blocks = 1/CU. LDS 88 KB: A[2][128][64] 32K | B[2][192][64]
// 48K | X[2][2048] 8K. Proven XOR swizzle chunk^(row&7) on A and B.
//
// Workspace: xb 64x2048 f16 (262144 B) | Wb 256x2048 f16 (1048576 B) |
// GT 768x2048 f16 (3145728 B) = 4,456,448 B total.

#define F_GENES 2000
#define KPAD    2048
#define P_PATH  256
#define EMB     768
#define BATCH   64
#define NT      32        // K tiles of BK=64

typedef _Float16 f16x8 __attribute__((ext_vector_type(8)));
typedef float    f32x4 __attribute__((ext_vector_type(4)));

__device__ __forceinline__ unsigned short f2h(float f) {
    union { _Float16 h; unsigned short s; } v; v.h = (_Float16)f; return v.s;
}

__device__ __forceinline__ void gload16(const void* g, void* l) {
    __builtin_amdgcn_global_load_lds((const __attribute__((address_space(1))) void*)g,
                                     (__attribute__((address_space(3))) void*)l,
                                     16, 0, 0);
}

// K1: pack x (64 rows) + W (256 rows) fp32 -> fp16, K-padded to 2048 w/ zeros.
__global__ void pack_xw_kernel(const float* __restrict__ x,
                               const float* __restrict__ w,
                               unsigned short* __restrict__ xb,
                               unsigned short* __restrict__ wb) {
    int gid = blockIdx.x * 256 + threadIdx.x;
    int row = gid >> 8;
    int s   = gid & 255;
    int d0  = s * 8;
    const float* src;
    unsigned short* dst;
    if (row < BATCH) { src = x + (size_t)row * F_GENES;           dst = xb + (size_t)row * KPAD; }
    else             { src = w + (size_t)(row - BATCH) * F_GENES; dst = wb + (size_t)(row - BATCH) * KPAD; }
    uint4 ov = make_uint4(0u, 0u, 0u, 0u);
    if (s < 250) {
        float4 v0 = *(const float4*)(src + d0);
        float4 v1 = *(const float4*)(src + d0 + 4);
        unsigned short* os = (unsigned short*)&ov;
        os[0] = f2h(v0.x); os[1] = f2h(v0.y); os[2] = f2h(v0.z); os[3] = f2h(v0.w);
        os[4] = f2h(v1.x); os[5] = f2h(v1.y); os[6] = f2h(v1.z); os[7] = f2h(v1.w);
    }
    *(uint4*)(dst + d0) = ov;
}

// K2: GT[n,k] = f16(GE[k,n]), k-padded to 2048.
__global__ void transpose_ge_kernel(const float* __restrict__ ge,
                                    unsigned short* __restrict__ GT) {
    __shared__ unsigned short tile[64][40];
    int kt = blockIdx.x & 63;
    int nt = blockIdx.x >> 6;
    int k0 = kt * 32, n0 = nt * 64;
    int t  = threadIdx.x;
    int kr = t >> 4;
    int nc = (t & 15) * 4;
#pragma unroll
    for (int p = 0; p < 2; ++p) {
        int k = k0 + p * 16 + kr;
        float4 v = make_float4(0.f, 0.f, 0.f, 0.f);
        if (k < F_GENES) v = *(const float4*)(ge + (size_t)k * EMB + n0 + nc);
        int kk = p * 16 + kr;
        tile[nc + 0][kk] = f2h(v.x);
        tile[nc + 1][kk] = f2h(v.y);
        tile[nc + 2][kk] = f2h(v.z);
        tile[nc + 3][kk] = f2h(v.w);
    }
    __syncthreads();
    int n  = t >> 2;
    int kc = (t & 3) * 8;
    uint4 o;
    unsigned short* os = (unsigned short*)&o;
#pragma unroll
    for (int j = 0; j < 8; ++j) os[j] = tile[n][kc + j];
    *(uint4*)(GT + (size_t)(n0 + n) * KPAD + k0 + kc) = o;
}

// ---- GEMM: 2-batch-shared 128x192 tile, 4 waves, depth-2 prefetch ----
// LDS (f16 units): A [2 dbuf][128 row][64 k] @0      (16384 f16, 32 KB)
//                  B [2 dbuf][192 row][64 k] @16384  (24576 f16, 48 KB)
//                  X [2 b][2048 k]           @40960  ( 4096 f16,  8 KB)
#define A_OFF 0
#define B_OFF 16384
#define X_OFF 40960

__global__ __launch_bounds__(256, 1)
void gemm_kernel(const _Float16* __restrict__ xb, const _Float16* __restrict__ Wb,
                 const _Float16* __restrict__ GT, const float* __restrict__ bias,
                 float* __restrict__ out) {
    __shared__ __align__(16) _Float16 smem[45056];   // 88 KB -> 1 block/CU

    const int tid  = threadIdx.x;
    const int wv   = tid >> 6;        // wave 0..3
    const int l    = tid & 63;
    const int quad = l >> 4;
    const int ln   = l & 15;
    const int wm   = wv >> 1;         // 0..1 (M half: 64 p-rows)
    const int wn   = wv & 1;          // 0..1 (N half: 96 cols)

    const int ct = blockIdx.x & 3;          // 768 / 192
    const int ph = (blockIdx.x >> 2) & 1;   // pathway half (128 rows of W)
    const int bp = blockIdx.x >> 3;         // batch pair 0..31
    const int b0 = 2 * bp;

    // staging thread->element maps: row = call*32 + (tid>>3), chunk = tid&7,
    // source chunk = (tid&7) ^ (row&7); row&7 == (tid>>3)&7 (call*32 == 0 mod 8)
    const int srow  = tid >> 3;
    const int schk  = (tid & 7) ^ (srow & 7);
    const _Float16* Ag = Wb + (size_t)(ph * 128 + srow) * KPAD + schk * 8;
    const _Float16* Bg = GT + (size_t)(ct * 192 + srow) * KPAD + schk * 8;

    // stage a full K-tile kt into dbuf d: A 4 calls + B 6 calls (4 KB each)
#define STAGE_ALL(d, kt) do {                                                   \
    _Pragma("unroll")                                                           \
    for (int c = 0; c < 4; ++c)                                                 \
        gload16(Ag + (size_t)c * 32 * KPAD + (kt) * 64,                         \
                smem + A_OFF + (d) * 8192 + c * 2048 + wv * 512);               \
    _Pragma("unroll")                                                           \
    for (int c = 0; c < 6; ++c)                                                 \
        gload16(Bg + (size_t)c * 32 * KPAD + (kt) * 64,                         \
                smem + B_OFF + (d) * 12288 + c * 2048 + wv * 512);              \
} while (0)

    // ---- prologue: X rows b0,b0+1 (2 calls) + tile0 (10 calls); drain ----
    gload16(xb + (size_t)b0 * KPAD + tid * 8,       smem + X_OFF + wv * 512);
    gload16(xb + (size_t)(b0 + 1) * KPAD + tid * 8, smem + X_OFF + 2048 + wv * 512);
    STAGE_ALL(0, 0);
    __syncthreads();

    f32x4 acc[2][4][6];
#pragma unroll
    for (int bb = 0; bb < 2; ++bb)
#pragma unroll
        for (int i = 0; i < 4; ++i)
#pragma unroll
            for (int j = 0; j < 6; ++j)
                acc[bb][i][j] = (f32x4){0.f, 0.f, 0.f, 0.f};

    const _Float16* As = smem + A_OFF;
    const _Float16* Bs = smem + B_OFF;
    const _Float16* Xs = smem + X_OFF;

    for (int t = 0; t < NT; ++t) {
        const int d = t & 1;
        // depth-2: issue next tile's staging first; lands before next barrier
        if (t + 1 < NT) STAGE_ALL(d ^ 1, t + 1);

        // compute tile t (open region - compiler pipelines kh0/kh1 freely)
#pragma unroll
        for (int kh = 0; kh < 2; ++kh) {
            const int swz = ((kh * 4 + quad) ^ (ln & 7)) * 8;
            f16x8 xq0 = *(const f16x8*)(Xs + t * 64 + kh * 32 + quad * 8);
            f16x8 xq1 = *(const f16x8*)(Xs + 2048 + t * 64 + kh * 32 + quad * 8);
            f16x8 af0[4], af1[4], bf[6];
#pragma unroll
            for (int mf = 0; mf < 4; ++mf) {
                f16x8 wf = *(const f16x8*)(As + d * 8192
                              + (wm * 64 + mf * 16 + ln) * 64 + swz);
                af0[mf] = wf * xq0;             // v_pk_mul_f16 x4 per frag
                af1[mf] = wf * xq1;
            }
#pragma unroll
            for (int nf = 0; nf < 6; ++nf)
                bf[nf] = *(const f16x8*)(Bs + d * 12288
                              + (wn * 96 + nf * 16 + ln) * 64 + swz);
#pragma unroll
            for (int mf = 0; mf < 4; ++mf)
#pragma unroll
                for (int nf = 0; nf < 6; ++nf) {
                    acc[0][mf][nf] = __builtin_amdgcn_mfma_f32_16x16x32_f16(
                        af0[mf], bf[nf], acc[0][mf][nf], 0, 0, 0);
                    acc[1][mf][nf] = __builtin_amdgcn_mfma_f32_16x16x32_f16(
                        af1[mf], bf[nf], acc[1][mf][nf], 0, 0, 0);
                }
        }

        // single barrier/tile: publishes dbuf d free + drains t+1's staging
        // (issued a full tile ago -> drain is cheap, unlike R5's same-tile)
        __syncthreads();
    }

    // ---- epilogue: C/D layout col=ln, row=quad*4+reg (m89/m91-verified) ----
#pragma unroll
    for (int bb = 0; bb < 2; ++bb) {
        const size_t obase = (size_t)(b0 + bb) * P_PATH * EMB;
#pragma unroll
        for (int mf = 0; mf < 4; ++mf) {
#pragma unroll
            for (int reg = 0; reg < 4; ++reg) {
                int p = ph * 128 + wm * 64 + mf * 16 + quad * 4 + reg;
                float bv = bias[p];
                size_t ro = obase + (size_t)p * EMB + ct * 192 + wn * 96 + ln;
#pragma unroll
                for (int nf = 0; nf < 6; ++nf)
                    out[ro + nf * 16] = acc[bb][mf][nf][reg] + bv;
            }
        }
    }
}

extern "C" void kernel_launch(void* const* d_in, const int* in_sizes, int n_in,
                              void* d_out, int out_size, void* d_ws, size_t ws_size,
                              hipStream_t stream) {
    // inputs (fp32): x(64x2000), weight(256x2000), bias(256), mask(unused), ge(2000x768)
    const float* x    = (const float*)d_in[0];
    const float* wgt  = (const float*)d_in[1];
    const float* bias = (const float*)d_in[2];
    const float* ge   = (const float*)d_in[4];
    float* out = (float*)d_out;

    char* ws = (char*)d_ws;
    unsigned short* xbuf = (unsigned short*)ws;                        // 262144 B
    unsigned short* Wbuf = (unsigned short*)(ws + 262144);             // 1048576 B
    unsigned short* GTb  = (unsigned short*)(ws + 262144 + 1048576);   // 3145728 B

    pack_xw_kernel<<<((BATCH + P_PATH) * 256) / 256, 256, 0, stream>>>(x, wgt, xbuf, Wbuf);
    transpose_ge_kernel<<<64 * 12, 256, 0, stream>>>(ge, GTb);
    gemm_kernel<<<dim3(256), dim3(256), 0, stream>>>(
        (const _Float16*)xbuf, (const _Float16*)Wbuf, (const _Float16*)GTb, bias, out);
}

// Round 7
// 120.206 us; speedup vs baseline: 1.1187x; 1.1187x over previous
//
#include <hip/hip_runtime.h>
#include <stdint.h>
#include <stddef.h>

// out[b, p*768+e] = sum_d x[b,d]*W[p,d]*GE[d,e] + bias[p]
// == per-b GEMM: OUT_b(256x768) = (diag(x_b) W)(256x2048) @ GT^T + bias
//
// R12 vs R11: refined law - pipe-sum is achieved ONLY with >=2 waves/SIMD
// (R11's 1/SIMD exposed waits on top of its sum); and in R5..R10 the LDS
// port (2000-2600 cyc/tile/CU) exceeded MFMA (1548/SIMD/tile) -> 33% cap.
// R12 = batch-share x4 AND 2 waves/SIMD: block 4b x 128p x 96e, 512 thr
// (8 waves 4wm x 2wn, wave 32p x 48e per b), grid 16bq x 2ph x 8ct = 256
// = 1/CU. W/GT frags read once per 4 batch elements (x applied via
// v_pk_mul on A-frag; X read from LDS is same-address broadcast = free).
// Per tile/CU: reads 80 b128 ~800cyc + X ~200 + writes 28KB ~220 = ~1200
// < MFMA 1548 -> MFMA-bound at last. acc 4x2x3 f32x4 = 96 VGPR, total
// ~180 -> launch_bounds(512,2) holds 2 waves/SIMD. LDS 72 KB.
// Keeps R11 skeleton: depth-2 prefetch, ONE __syncthreads/tile (drains
// loads issued a full tile ~1500cyc earlier - L2 latency long gone),
// no sched_barriers (compiler interleaves), proven XOR swizzles.
//
// Workspace: xb 64x2048 f16 (262144 B) | Wb 256x2048 f16 (1048576 B) |
// GT 768x2048 f16 (3145728 B) = 4,456,448 B total.

#define F_GENES 2000
#define KPAD    2048
#define P_PATH  256
#define EMB     768
#define BATCH   64
#define NT      32        // K tiles of BK=64

typedef _Float16 f16x8 __attribute__((ext_vector_type(8)));
typedef float    f32x4 __attribute__((ext_vector_type(4)));

__device__ __forceinline__ unsigned short f2h(float f) {
    union { _Float16 h; unsigned short s; } v; v.h = (_Float16)f; return v.s;
}

__device__ __forceinline__ void gload16(const void* g, void* l) {
    __builtin_amdgcn_global_load_lds((const __attribute__((address_space(1))) void*)g,
                                     (__attribute__((address_space(3))) void*)l,
                                     16, 0, 0);
}

// K1: pack x (64 rows) + W (256 rows) fp32 -> fp16, K-padded to 2048 w/ zeros.
__global__ void pack_xw_kernel(const float* __restrict__ x,
                               const float* __restrict__ w,
                               unsigned short* __restrict__ xb,
                               unsigned short* __restrict__ wb) {
    int gid = blockIdx.x * 256 + threadIdx.x;
    int row = gid >> 8;
    int s   = gid & 255;
    int d0  = s * 8;
    const float* src;
    unsigned short* dst;
    if (row < BATCH) { src = x + (size_t)row * F_GENES;           dst = xb + (size_t)row * KPAD; }
    else             { src = w + (size_t)(row - BATCH) * F_GENES; dst = wb + (size_t)(row - BATCH) * KPAD; }
    uint4 ov = make_uint4(0u, 0u, 0u, 0u);
    if (s < 250) {
        float4 v0 = *(const float4*)(src + d0);
        float4 v1 = *(const float4*)(src + d0 + 4);
        unsigned short* os = (unsigned short*)&ov;
        os[0] = f2h(v0.x); os[1] = f2h(v0.y); os[2] = f2h(v0.z); os[3] = f2h(v0.w);
        os[4] = f2h(v1.x); os[5] = f2h(v1.y); os[6] = f2h(v1.z); os[7] = f2h(v1.w);
    }
    *(uint4*)(dst + d0) = ov;
}

// K2: GT[n,k] = f16(GE[k,n]), k-padded to 2048.
__global__ void transpose_ge_kernel(const float* __restrict__ ge,
                                    unsigned short* __restrict__ GT) {
    __shared__ unsigned short tile[64][40];
    int kt = blockIdx.x & 63;
    int nt = blockIdx.x >> 6;
    int k0 = kt * 32, n0 = nt * 64;
    int t  = threadIdx.x;
    int kr = t >> 4;
    int nc = (t & 15) * 4;
#pragma unroll
    for (int p = 0; p < 2; ++p) {
        int k = k0 + p * 16 + kr;
        float4 v = make_float4(0.f, 0.f, 0.f, 0.f);
        if (k < F_GENES) v = *(const float4*)(ge + (size_t)k * EMB + n0 + nc);
        int kk = p * 16 + kr;
        tile[nc + 0][kk] = f2h(v.x);
        tile[nc + 1][kk] = f2h(v.y);
        tile[nc + 2][kk] = f2h(v.z);
        tile[nc + 3][kk] = f2h(v.w);
    }
    __syncthreads();
    int n  = t >> 2;
    int kc = (t & 3) * 8;
    uint4 o;
    unsigned short* os = (unsigned short*)&o;
#pragma unroll
    for (int j = 0; j < 8; ++j) os[j] = tile[n][kc + j];
    *(uint4*)(GT + (size_t)(n0 + n) * KPAD + k0 + kc) = o;
}

// ---- GEMM: 4-batch-shared 128x96 tile, 8 waves, depth-2 prefetch ----
// LDS (f16 units): A [2 dbuf][128 row][64 k] @0      (16384 f16, 32 KB)
//                  B [2 dbuf][ 96 row][64 k] @16384  (12288 f16, 24 KB)
//                  X [4 b][2048 k]           @28672  ( 8192 f16, 16 KB)
#define A_OFF 0
#define B_OFF 16384
#define X_OFF 28672

__global__ __launch_bounds__(512, 2)
void gemm_kernel(const _Float16* __restrict__ xb, const _Float16* __restrict__ Wb,
                 const _Float16* __restrict__ GT, const float* __restrict__ bias,
                 float* __restrict__ out) {
    __shared__ __align__(16) _Float16 smem[36864];   // 72 KB

    const int tid  = threadIdx.x;
    const int wv   = tid >> 6;        // wave 0..7
    const int l    = tid & 63;
    const int quad = l >> 4;
    const int ln   = l & 15;
    const int wm   = wv >> 1;         // 0..3 (32 p-rows each)
    const int wn   = wv & 1;          // 0..1 (48 cols each)

    const int ct = blockIdx.x & 7;          // 768 / 96
    const int ph = (blockIdx.x >> 3) & 1;   // pathway half (128 rows of W)
    const int bq = blockIdx.x >> 4;         // batch quad 0..15
    const int b0 = 4 * bq;

    // staging maps: 512 threads, row = tid>>3 (0..63), chunk = tid&7,
    // source chunk = (tid&7) ^ (row&7); LDS dest = base + tid*8 (linear) ✓
    const int srow = tid >> 3;
    const int schk = (tid & 7) ^ (srow & 7);
    const _Float16* Ag = Wb + (size_t)(ph * 128 + srow) * KPAD + schk * 8;
    const _Float16* Bg = GT + (size_t)(ct * 96 + srow) * KPAD + schk * 8;

    // stage K-tile kt into dbuf d: A 2 calls (64 rows) + B 1.5 calls (96 rows)
#define STAGE_TILE(d, kt) do {                                                  \
    gload16(Ag + (kt) * 64,                  smem + A_OFF + (d) * 8192 + tid * 8); \
    gload16(Ag + (size_t)64 * KPAD + (kt) * 64,                                 \
            smem + A_OFF + (d) * 8192 + 4096 + tid * 8);                        \
    gload16(Bg + (kt) * 64,                  smem + B_OFF + (d) * 6144 + tid * 8); \
    if (tid < 256)                                                              \
        gload16(Bg + (size_t)64 * KPAD + (kt) * 64,                             \
                smem + B_OFF + (d) * 6144 + 4096 + tid * 8);                    \
} while (0)

    // ---- prologue: X (4 rows, 2 calls) + tile0; one full drain ----
    {
        const _Float16* xg = xb + (size_t)(b0 + (tid >> 8)) * KPAD + (tid & 255) * 8;
        gload16(xg,                  smem + X_OFF + tid * 8);
        gload16(xg + 2 * KPAD,       smem + X_OFF + 4096 + tid * 8);
    }
    STAGE_TILE(0, 0);
    __syncthreads();

    f32x4 acc[4][2][3];
#pragma unroll
    for (int bb = 0; bb < 4; ++bb)
#pragma unroll
        for (int i = 0; i < 2; ++i)
#pragma unroll
            for (int j = 0; j < 3; ++j)
                acc[bb][i][j] = (f32x4){0.f, 0.f, 0.f, 0.f};

    const _Float16* As = smem + A_OFF;
    const _Float16* Bs = smem + B_OFF;
    const _Float16* Xs = smem + X_OFF;

    for (int t = 0; t < NT; ++t) {
        const int d = t & 1;
        // depth-2: issue next tile's staging first; lands long before its use
        if (t + 1 < NT) STAGE_TILE(d ^ 1, t + 1);

        // compute tile t (open region - compiler pipelines kh0/kh1 freely)
#pragma unroll
        for (int kh = 0; kh < 2; ++kh) {
            const int swz = ((kh * 4 + quad) ^ (ln & 7)) * 8;
            f16x8 bf[3];
#pragma unroll
            for (int nf = 0; nf < 3; ++nf)
                bf[nf] = *(const f16x8*)(Bs + d * 6144
                              + (wn * 48 + nf * 16 + ln) * 64 + swz);
            f16x8 xq[4];
#pragma unroll
            for (int bb = 0; bb < 4; ++bb)   // same-address broadcast per quad
                xq[bb] = *(const f16x8*)(Xs + bb * 2048 + t * 64 + kh * 32 + quad * 8);
#pragma unroll
            for (int mf = 0; mf < 2; ++mf) {
                f16x8 wf = *(const f16x8*)(As + d * 8192
                              + (wm * 32 + mf * 16 + ln) * 64 + swz);
#pragma unroll
                for (int bb = 0; bb < 4; ++bb) {
                    f16x8 af = wf * xq[bb];          // v_pk_mul_f16 x4
#pragma unroll
                    for (int nf = 0; nf < 3; ++nf)
                        acc[bb][mf][nf] = __builtin_amdgcn_mfma_f32_16x16x32_f16(
                            af, bf[nf], acc[bb][mf][nf], 0, 0, 0);
                }
            }
        }

        // single barrier/tile: publishes dbuf free + drains t+1's staging
        __syncthreads();
    }

    // ---- epilogue: C/D layout col=ln, row=quad*4+reg (m89/m91-verified) ----
#pragma unroll
    for (int bb = 0; bb < 4; ++bb) {
        const size_t obase = (size_t)(b0 + bb) * P_PATH * EMB;
#pragma unroll
        for (int mf = 0; mf < 2; ++mf) {
#pragma unroll
            for (int reg = 0; reg < 4; ++reg) {
                int p = ph * 128 + wm * 32 + mf * 16 + quad * 4 + reg;
                float bv = bias[p];
                size_t ro = obase + (size_t)p * EMB + ct * 96 + wn * 48 + ln;
#pragma unroll
                for (int nf = 0; nf < 3; ++nf)
                    out[ro + nf * 16] = acc[bb][mf][nf][reg] + bv;
            }
        }
    }
}

extern "C" void kernel_launch(void* const* d_in, const int* in_sizes, int n_in,
                              void* d_out, int out_size, void* d_ws, size_t ws_size,
                              hipStream_t stream) {
    // inputs (fp32): x(64x2000), weight(256x2000), bias(256), mask(unused), ge(2000x768)
    const float* x    = (const float*)d_in[0];
    const float* wgt  = (const float*)d_in[1];
    const float* bias = (const float*)d_in[2];
    const float* ge   = (const float*)d_in[4];
    float* out = (float*)d_out;

    char* ws = (char*)d_ws;
    unsigned short* xbuf = (unsigned short*)ws;                        // 262144 B
    unsigned short* Wbuf = (unsigned short*)(ws + 262144);             // 1048576 B
    unsigned short* GTb  = (unsigned short*)(ws + 262144 + 1048576);   // 3145728 B

    pack_xw_kernel<<<((BATCH + P_PATH) * 256) / 256, 256, 0, stream>>>(x, wgt, xbuf, Wbuf);
    transpose_ge_kernel<<<64 * 12, 256, 0, stream>>>(ge, GTb);
    gemm_kernel<<<dim3(256), dim3(512), 0, stream>>>(
        (const _Float16*)xbuf, (const _Float16*)Wbuf, (const _Float16*)GTb, bias, out);
}